// Round 13
// baseline (256.153 us; speedup 1.0000x reference)
//
#include <hip/hip_runtime.h>
#include <math.h>

// ---------------------------------------------------------------------------
// Deformable transformer layer, MI355X round-13:
//  - NEW gemm_fullk core (64x128 tile): entire 256-k B panel staged to LDS
//    in ONE shot (64 KB), A stripe held in REGISTERS (16x short8/lane via
//    plain global loads) -> ONE vmcnt drain per 256-k chunk instead of 4.
//    K-loop body is pure ds_read+MFMA (no global, no barriers).
//    Used for oa_v, Wf1, Wf2 (K=1024 -> 4 chunks).
//  - wp_ln2 / prep_all / deform_fused unchanged from round-12.
//  6 dispatches.
// B=2, Nq=8192, C=256, HEADS=8, dh=32, LEVELS=3, POINTS=4, MLP=4
// ---------------------------------------------------------------------------

typedef short short8 __attribute__((ext_vector_type(8)));
typedef short s16x4 __attribute__((ext_vector_type(4)));
typedef __bf16 bf16x8 __attribute__((ext_vector_type(8)));
typedef float f32x4 __attribute__((ext_vector_type(4)));

__device__ __forceinline__ short f2b(float f) {
  unsigned u = __builtin_bit_cast(unsigned, f);
  u += 0x7fffu + ((u >> 16) & 1u);   // RNE to bf16
  return (short)(u >> 16);
}
__device__ __forceinline__ float b2f(short s) {
  unsigned u = ((unsigned)(unsigned short)s) << 16;
  return __builtin_bit_cast(float, u);
}
__device__ __forceinline__ void b8f(short8 s, float* f) {
  const uint4 u = __builtin_bit_cast(uint4, s);
  f[0] = __builtin_bit_cast(float, u.x << 16);
  f[1] = __builtin_bit_cast(float, u.x & 0xffff0000u);
  f[2] = __builtin_bit_cast(float, u.y << 16);
  f[3] = __builtin_bit_cast(float, u.y & 0xffff0000u);
  f[4] = __builtin_bit_cast(float, u.z << 16);
  f[5] = __builtin_bit_cast(float, u.z & 0xffff0000u);
  f[6] = __builtin_bit_cast(float, u.w << 16);
  f[7] = __builtin_bit_cast(float, u.w & 0xffff0000u);
}

__device__ __forceinline__ f32x4 mfma16(short8 a, short8 b, f32x4 c) {
  return __builtin_amdgcn_mfma_f32_16x16x32_bf16(
      __builtin_bit_cast(bf16x8, a), __builtin_bit_cast(bf16x8, b), c, 0, 0, 0);
}

typedef __attribute__((address_space(3))) unsigned int lds_u32;
typedef const __attribute__((address_space(1))) unsigned int glb_u32;
__device__ __forceinline__ void glds16(const void* g, void* l) {
  __builtin_amdgcn_global_load_lds((glb_u32*)g, (lds_u32*)l, 16, 0, 0);
}

__device__ __forceinline__ float gelu1(float v) {
  return 0.5f * v * (1.f + erff(v * 0.70710678118654752f));
}

// ---------------------------------------------------------------------------
// gemm_fullk core: 64x128 tile. Per 256-k chunk: stage full B panel
// (4 k-tiles x [128][64] = 64 KB) via glds + load A stripe into registers
// (2 rows x 8 short8/lane), ONE barrier, then 8 pure ds_read+MFMA steps.
// K must be a multiple of 256. 8-chunk rotation swizzle, swapped MFMA,
// LDS-staged coalesced epilogue (reuses sB region).
// EPI: 1=gelu->bf16 | 3=f32: bias+f32 add1 | 4=oa (bias split 192/96, f32)
//      5=bf16+bias
// ---------------------------------------------------------------------------
template <int EPI>
__device__ __forceinline__ void gemm_fullk_core(
    int bx, int by,
    const short* __restrict__ A, const short* __restrict__ Bt,
    const float* __restrict__ bias, const float* __restrict__ bias2,
    const void* __restrict__ add1,
    void* __restrict__ Cout, int M, int Nreal, int ldc, int K, char* smem)
{
  short* sB = (short*)smem;       // 4 x [128][64] shorts = 64 KB
  float* sf = (float*)smem;       // epilogue staging [32][132] (reuse)

  const int t = threadIdx.x;
  const int wave = t >> 6, lane = t & 63;
  const int quad = lane >> 4, l16 = lane & 15;
  const int wm = (wave & 1) * 32, wn = (wave >> 1) * 64;
  const int m0 = by * 64, n0 = bx * 128;

  f32x4 acc[2][4];
#pragma unroll
  for (int i = 0; i < 2; i++)
#pragma unroll
    for (int j = 0; j < 4; j++) acc[i][j] = (f32x4){0.f, 0.f, 0.f, 0.f};

  // B staging: lane L: srow=L>>3, pos=L&7; stages global k-chunk (pos+srow)&7
  // at LDS position pos of its row (glds dest = base + L*16B).
  const int srow = lane >> 3, pos = lane & 7;
  const int chunk = (pos + srow) & 7;
  const short* gB = Bt + (size_t)(n0 + wave * 32 + srow) * K + chunk * 8;
  // A stripe: lane owns rows wm+l16 and wm+16+l16; k window quad*8 per step.
  const short* gA0 = A + (size_t)(m0 + wm + l16) * K + quad * 8;
  const short* gA1 = gA0 + (size_t)16 * K;

  const int nkt = K >> 8;
  for (int kt2 = 0; kt2 < nkt; ++kt2) {
    if (kt2) __syncthreads();          // all reads of sB done before overwrite
    const int ko2 = kt2 * 256;
    // stage full 256-k B panel (16 glds/thread)
#pragma unroll
    for (int kt = 0; kt < 4; ++kt)
#pragma unroll
      for (int g = 0; g < 4; ++g)
        glds16(gB + ko2 + kt * 64 + (size_t)(g * 8) * K,
               sB + kt * 8192 + (wave * 32 + g * 8) * 64);
    // A stripe into registers (drained by the same barrier as the glds)
    short8 afr[2][8];
#pragma unroll
    for (int s = 0; s < 8; ++s) {
      afr[0][s] = *(const short8*)(gA0 + ko2 + s * 32);
      afr[1][s] = *(const short8*)(gA1 + ko2 + s * 32);
    }
    __syncthreads();                   // single vmcnt(0) drain per chunk
    // pure compute: 8 steps, zero global ops, zero barriers
#pragma unroll
    for (int s = 0; s < 8; ++s) {
      const int kt = s >> 1;
      const int c = (s & 1) * 4 + quad;
      short8 bf[4];
#pragma unroll
      for (int j = 0; j < 4; j++) {
        const int lrB = wn + j * 16 + l16;
        bf[j] = *(const short8*)&sB[kt * 8192 + lrB * 64 + ((c - lrB) & 7) * 8];
      }
#pragma unroll
      for (int i = 0; i < 2; i++)
#pragma unroll
        for (int j = 0; j < 4; j++)
          acc[i][j] = mfma16(bf[j], afr[i][s], acc[i][j]);
    }
  }
  __syncthreads();

  // Epilogue: 2 bands of 32 rows x 128 cols, coalesced full-line stores.
#pragma unroll
  for (int b = 0; b < 2; ++b) {
    if (wm == b * 32) {
#pragma unroll
      for (int i = 0; i < 2; ++i) {
        const int rr = i * 16 + l16;
#pragma unroll
        for (int j = 0; j < 4; ++j)
          *(f32x4*)&sf[rr * 132 + wn + quad * 4 + j * 16] = acc[i][j];
      }
    }
    __syncthreads();
#pragma unroll
    for (int r2 = 0; r2 < 4; ++r2) {
      const int fidx = r2 * 1024 + t * 4;
      const int row = fidx >> 7, col = fidx & 127;
      const int gm = m0 + b * 32 + row;
      const int cc = n0 + col;
      if (gm < M && cc < Nreal) {
        const float4 v = *(const float4*)&sf[row * 132 + col];
        float4 bb;
        if (EPI == 4) bb = (cc < 192) ? *(const float4*)(bias + cc)
                                      : *(const float4*)(bias2 + cc - 192);
        else bb = *(const float4*)(bias + cc);
        float v0 = v.x + bb.x, v1 = v.y + bb.y, v2 = v.z + bb.z, v3 = v.w + bb.w;
        if (EPI == 1) {
          v0 = gelu1(v0); v1 = gelu1(v1); v2 = gelu1(v2); v3 = gelu1(v3);
          s16x4 o; o.x = f2b(v0); o.y = f2b(v1); o.z = f2b(v2); o.w = f2b(v3);
          *(s16x4*)((short*)Cout + (size_t)gm * ldc + cc) = o;
        } else if (EPI == 5) {
          s16x4 o; o.x = f2b(v0); o.y = f2b(v1); o.z = f2b(v2); o.w = f2b(v3);
          *(s16x4*)((short*)Cout + (size_t)gm * ldc + cc) = o;
        } else {
          if (EPI == 3) {
            const float4 a1 = *(const float4*)((const float*)add1 + (size_t)gm * ldc + cc);
            v0 += a1.x; v1 += a1.y; v2 += a1.z; v3 += a1.w;
          }
          *(float4*)((float*)Cout + (size_t)gm * ldc + cc) =
              make_float4(v0, v1, v2, v3);
        }
      }
    }
    __syncthreads();
  }
}

template <int EPI>
__global__ __launch_bounds__(256) void gemm_fullk_k(
    const short* __restrict__ A, const short* __restrict__ Bt,
    const float* __restrict__ bias, const void* __restrict__ add1,
    void* __restrict__ Cout, int M, int Nreal, int ldc, int K)
{
  __shared__ __align__(16) char smem[65536];
  gemm_fullk_core<EPI>(blockIdx.x, blockIdx.y, A, Bt, bias, nullptr, add1,
                       Cout, M, Nreal, ldc, K, smem);
}

// Merged: blocks [0,768) -> oa GEMM (EPI4), [768,1162) -> v GEMM (EPI5)
__global__ __launch_bounds__(256) void gemm_oa_v(
    const short* __restrict__ qa, const short* __restrict__ wt_oa,
    const float* __restrict__ bo, const float* __restrict__ ba,
    float* __restrict__ oabuf,
    const short* __restrict__ valbf, const short* __restrict__ wt_v,
    const float* __restrict__ bv, short* __restrict__ vproj)
{
  __shared__ __align__(16) char smem[65536];
  const int idx = blockIdx.x;
  if (idx < 768) {
    gemm_fullk_core<4>(idx % 3, idx / 3, qa, wt_oa, bo, ba, nullptr,
                       oabuf, 16384, 288, 288, 256, smem);
  } else {
    const int r = idx - 768;
    gemm_fullk_core<5>(r % 2, r / 2, valbf, wt_v, bv, nullptr, nullptr,
                       vproj, 12600, 256, 256, 256, smem);
  }
}

// ---------------------------------------------------------------------------
// gemm_wp_ln2: 32x256 tile, block owns COMPLETE rows (round-12, proven).
// qbuf = acc + bp + b2f(qnb) + query; q2 = LN(qbuf; g2,b2) fused epilogue.
// ---------------------------------------------------------------------------
__global__ __launch_bounds__(256) void gemm_wp_ln2(
    const short* __restrict__ A, const short* __restrict__ Bt,
    const float* __restrict__ bias,
    const short* __restrict__ qnb, const float* __restrict__ query,
    const float* __restrict__ g2, const float* __restrict__ b2v,
    float* __restrict__ qbuf, short* __restrict__ q2)
{
  __shared__ __align__(16) char smem[36864];
  short* sA = (short*)smem;        // [32][64] shorts (4 KB)
  short* sB = sA + 2048;           // [256][64] shorts (32 KB)
  float* sf = (float*)smem;        // epilogue staging [32][260]

  const int t = threadIdx.x;
  const int wave = t >> 6, lane = t & 63;
  const int quad = lane >> 4, l16 = lane & 15;
  const int wm = (wave & 1) * 16, wn = (wave >> 1) * 128;
  const int m0 = blockIdx.x * 32;
  const int K = 256;

  f32x4 acc[8];
#pragma unroll
  for (int j = 0; j < 8; j++) acc[j] = (f32x4){0.f, 0.f, 0.f, 0.f};

  const int srow = lane >> 3, pos = lane & 7;
  const int chunk = (pos + srow) & 7;
  const short* gA = A + (size_t)(m0 + wave * 8 + srow) * K + chunk * 8;
  const short* gB = Bt + (size_t)(wave * 64 + srow) * K + chunk * 8;

  for (int kt = 0; kt < 4; ++kt) {
    if (kt) __syncthreads();
    const int ko = kt * 64;
    glds16(gA + ko, sA + (wave * 8) * 64);
#pragma unroll
    for (int g = 0; g < 8; ++g)
      glds16(gB + ko + (size_t)(g * 8) * K, sB + (wave * 64 + g * 8) * 64);
    __syncthreads();
#pragma unroll
    for (int kk = 0; kk < 2; ++kk) {
      const int c = kk * 4 + quad;
      const int lrA = wm + l16;
      const short8 af = *(const short8*)&sA[lrA * 64 + ((c - lrA) & 7) * 8];
      short8 bf[8];
#pragma unroll
      for (int j = 0; j < 8; j++) {
        const int lrB = wn + j * 16 + l16;
        bf[j] = *(const short8*)&sB[lrB * 64 + ((c - lrB) & 7) * 8];
      }
#pragma unroll
      for (int j = 0; j < 8; j++) acc[j] = mfma16(bf[j], af, acc[j]);
    }
  }
  __syncthreads();

#pragma unroll
  for (int j = 0; j < 8; j++)
    *(f32x4*)&sf[(wm + l16) * 260 + wn + j * 16 + quad * 4] = acc[j];
  __syncthreads();

  const float4 bb   = *(const float4*)(bias + lane * 4);
  const float4 gv   = *(const float4*)(g2 + lane * 4);
  const float4 b2f4 = *(const float4*)(b2v + lane * 4);
#pragma unroll
  for (int rr = 0; rr < 8; ++rr) {
    const int row = wave * 8 + rr;
    const int gm = m0 + row;
    const float4 a = *(const float4*)&sf[row * 260 + lane * 4];
    const s16x4 qn = *(const s16x4*)(qnb + (size_t)gm * 256 + lane * 4);
    const float4 qv = *(const float4*)(query + (size_t)gm * 256 + lane * 4);
    float q0 = a.x + bb.x + b2f(qn.x) + qv.x;
    float q1 = a.y + bb.y + b2f(qn.y) + qv.y;
    float q2f = a.z + bb.z + b2f(qn.z) + qv.z;
    float q3 = a.w + bb.w + b2f(qn.w) + qv.w;
    float s = q0 + q1 + q2f + q3;
#pragma unroll
    for (int o = 32; o; o >>= 1) s += __shfl_xor(s, o);
    const float mean = s * (1.f / 256.f);
    const float d0 = q0 - mean, d1 = q1 - mean, d2 = q2f - mean, d3 = q3 - mean;
    float ss = d0 * d0 + d1 * d1 + d2 * d2 + d3 * d3;
#pragma unroll
    for (int o = 32; o; o >>= 1) ss += __shfl_xor(ss, o);
    const float inv = rsqrtf(ss * (1.f / 256.f) + 1e-5f);
    *(float4*)(qbuf + (size_t)gm * 256 + lane * 4) = make_float4(q0, q1, q2f, q3);
    s16x4 o2;
    o2.x = f2b(d0 * inv * gv.x + b2f4.x);
    o2.y = f2b(d1 * inv * gv.y + b2f4.y);
    o2.z = f2b(d2 * inv * gv.z + b2f4.z);
    o2.w = f2b(d3 * inv * gv.w + b2f4.w);
    *(s16x4*)(q2 + (size_t)gm * 256 + lane * 4) = o2;
  }
}

// ---------------------------------------------------------------------------
// prep_all: merged wconvert (1792 blocks) + vconvert (3169) + LN1 (4096).
// ---------------------------------------------------------------------------
__global__ __launch_bounds__(256) void prep_all(
    const float* __restrict__ Wo, const float* __restrict__ Wa,
    const float* __restrict__ Wv, const float* __restrict__ Wp,
    const float* __restrict__ Wf1, const float* __restrict__ Wf2,
    short* __restrict__ t_oa, short* __restrict__ t_v, short* __restrict__ t_p,
    short* __restrict__ t_f1, short* __restrict__ t_f2,
    const float* __restrict__ value, short* __restrict__ valbf,
    const float* __restrict__ query, const float* __restrict__ query_pos,
    const float* __restrict__ g1, const float* __restrict__ b1,
    short* __restrict__ qnb, short* __restrict__ qa)
{
  __shared__ float tile[32][33];
  const int t = threadIdx.x;
  const int blk = blockIdx.x;

  if (blk < 1792) {
    const int bxa = blk & 255, bya = blk >> 8;
    int K, N, noff; const float* src; short* dst;
    switch (bya) {
      case 0: src = Wo;      dst = t_oa; K = 256;  N = 192;  noff = 0;   break;
      case 1: src = Wa;      dst = t_oa; K = 256;  N = 96;   noff = 192; break;
      case 2: src = nullptr; dst = t_oa; K = 256;  N = 96;   noff = 288; break;
      case 3: src = Wv;      dst = t_v;  K = 256;  N = 256;  noff = 0;   break;
      case 4: src = Wp;      dst = t_p;  K = 256;  N = 256;  noff = 0;   break;
      case 5: src = Wf1;     dst = t_f1; K = 256;  N = 1024; noff = 0;   break;
      default: src = Wf2;    dst = t_f2; K = 1024; N = 256;  noff = 0;   break;
    }
    const int tilesK = K >> 5;
    const int nt = tilesK * (N >> 5);
    if (bxa >= nt) return;
    const int tk = bxa % tilesK, tn = bxa / tilesK;
    const int k0 = tk * 32, n0 = tn * 32;
    const int r = t >> 3, c4 = (t & 7) * 4;
    float4 v = make_float4(0.f, 0.f, 0.f, 0.f);
    if (src) v = *(const float4*)(src + (size_t)(k0 + r) * N + n0 + c4);
    tile[r][c4] = v.x; tile[r][c4 + 1] = v.y; tile[r][c4 + 2] = v.z; tile[r][c4 + 3] = v.w;
    __syncthreads();
    const int nn = t >> 3, kc = (t & 7) * 4;
    s16x4 o;
    o.x = f2b(tile[kc][nn]); o.y = f2b(tile[kc + 1][nn]);
    o.z = f2b(tile[kc + 2][nn]); o.w = f2b(tile[kc + 3][nn]);
    *(s16x4*)(dst + (size_t)(noff + n0 + nn) * K + k0 + kc) = o;
  } else if (blk < 1792 + 3169) {
    const int i = ((blk - 1792) * 256 + t) * 4;
    if (i >= 12672 * 256) return;
    s16x4 o = (s16x4){0, 0, 0, 0};
    if (i < 12600 * 256) {
      float4 v = *(const float4*)(value + i);
      o.x = f2b(v.x); o.y = f2b(v.y); o.z = f2b(v.z); o.w = f2b(v.w);
    }
    *(s16x4*)(valbf + i) = o;
  } else {
    const int row  = (blk - 4961) * 4 + (t >> 6);
    const int lane = t & 63;
    const float4 v = ((const float4*)(query + (size_t)row * 256))[lane];
    float s = v.x + v.y + v.z + v.w;
#pragma unroll
    for (int o = 32; o; o >>= 1) s += __shfl_xor(s, o);
    const float mean = s * (1.f / 256.f);
    const float dx = v.x - mean, dy = v.y - mean, dz = v.z - mean, dw = v.w - mean;
    float s2 = dx * dx + dy * dy + dz * dz + dw * dw;
#pragma unroll
    for (int o = 32; o; o >>= 1) s2 += __shfl_xor(s2, o);
    const float inv = rsqrtf(s2 * (1.f / 256.f) + 1e-5f);
    const float4 gv = ((const float4*)g1)[lane];
    const float4 bv = ((const float4*)b1)[lane];
    const float4 o1 = make_float4(dx * inv * gv.x + bv.x, dy * inv * gv.y + bv.y,
                                  dz * inv * gv.z + bv.z, dw * inv * gv.w + bv.w);
    s16x4 ob; ob.x = f2b(o1.x); ob.y = f2b(o1.y); ob.z = f2b(o1.z); ob.w = f2b(o1.w);
    ((s16x4*)(qnb + (size_t)row * 256))[lane] = ob;
    const float4 pv = ((const float4*)(query_pos + (size_t)row * 256))[lane];
    s16x4 op;
    op.x = f2b(o1.x + pv.x); op.y = f2b(o1.y + pv.y);
    op.z = f2b(o1.z + pv.z); op.w = f2b(o1.w + pv.w);
    ((s16x4*)(qa + (size_t)row * 256))[lane] = op;
  }
}

// ---------------------------------------------------------------------------
// deform_fused: block = 8 rows. Phase 1 (64 threads): softmax + bilinear
// setup -> LDS tables. Phase 2 (256 threads): pure gather+FMA.
// ---------------------------------------------------------------------------
__global__ __launch_bounds__(256) void deform_fused(
    const short* __restrict__ vproj, const float* __restrict__ oa,
    const float* __restrict__ refp, short* __restrict__ out)
{
  __shared__ int4 sIdx[768];
  __shared__ s16x4 sW[768];
  const int t = threadIdx.x;

  if (t < 64) {
    const int row = blockIdx.x * 8 + (t >> 3), h = t & 7;
    const float* oarow = oa + (size_t)row * 288;
    float off[24];
    const float4* op = (const float4*)(oarow + h * 24);
#pragma unroll
    for (int i = 0; i < 6; i++) {
      const float4 v = op[i];
      off[i * 4] = v.x; off[i * 4 + 1] = v.y; off[i * 4 + 2] = v.z; off[i * 4 + 3] = v.w;
    }
    float lg[12];
    const float4* ap = (const float4*)(oarow + 192 + h * 12);
#pragma unroll
    for (int i = 0; i < 3; i++) {
      const float4 v = ap[i];
      lg[i * 4] = v.x; lg[i * 4 + 1] = v.y; lg[i * 4 + 2] = v.z; lg[i * 4 + 3] = v.w;
    }
    const float* rp = refp + (size_t)row * 6;
    const float Rx[3] = {rp[0], rp[2], rp[4]}, Ry[3] = {rp[1], rp[3], rp[5]};
    float mx = lg[0];
#pragma unroll
    for (int i = 1; i < 12; i++) mx = fmaxf(mx, lg[i]);
    float sum = 0.f;
#pragma unroll
    for (int i = 0; i < 12; i++) { lg[i] = __expf(lg[i] - mx); sum += lg[i]; }
    const float inv = 1.f / sum;
    const int b = row >> 13;
    const int Hs[3] = {60, 30, 15}, Ws[3] = {80, 40, 20}, St[3] = {0, 4800, 6000};
#pragma unroll
    for (int p = 0; p < 12; p++) {
      const int l = p >> 2;
      const int W = Ws[l], H = Hs[l];
      const float gx = Rx[l] * W + off[p * 2]     - 0.5f;
      const float gy = Ry[l] * H + off[p * 2 + 1] - 0.5f;
      const float x0f = floorf(gx), y0f = floorf(gy);
      const float wx = gx - x0f, wy = gy - y0f;
      const int x0 = (int)x0f, y0 = (int)y0f;
      const float aw = lg[p] * inv;
      float cw[4] = {(1.f - wx) * (1.f - wy), wx * (1.f - wy),
                     (1.f - wx) * wy, wx * wy};
      const int base = b * 6300 + St[l];
      int ci[4];
#pragma unroll
      for (int k = 0; k < 4; k++) {
        const int xx = x0 + (k & 1), yy = y0 + (k >> 1);
        const bool valid = (xx >= 0) & (xx < W) & (yy >= 0) & (yy < H);
        const int xc = min(max(xx, 0), W - 1);
        const int yc = min(max(yy, 0), H - 1);
        ci[k] = ((base + yc * W + xc) << 8) + h * 32;
        cw[k] = valid ? cw[k] * aw : 0.f;
      }
      sIdx[t * 12 + p] = make_int4(ci[0], ci[1], ci[2], ci[3]);
      s16x4 wv; wv.x = f2b(cw[0]); wv.y = f2b(cw[1]); wv.z = f2b(cw[2]); wv.w = f2b(cw[3]);
      sW[t * 12 + p] = wv;
    }
  }
  __syncthreads();

  const int lu = t >> 2, c4 = (t & 3) * 8;
  float acc[8];
#pragma unroll
  for (int i = 0; i < 8; i++) acc[i] = 0.f;
#pragma unroll 2
  for (int p = 0; p < 12; p++) {
    const int4 idx = sIdx[lu * 12 + p];
    const s16x4 wb = sW[lu * 12 + p];
    const float w0 = b2f(wb.x), w1 = b2f(wb.y), w2 = b2f(wb.z), w3 = b2f(wb.w);
    const short8 v0 = *(const short8*)(vproj + idx.x + c4);
    const short8 v1 = *(const short8*)(vproj + idx.y + c4);
    const short8 v2 = *(const short8*)(vproj + idx.z + c4);
    const short8 v3 = *(const short8*)(vproj + idx.w + c4);
    float f0[8], f1[8], f2[8], f3[8];
    b8f(v0, f0); b8f(v1, f1); b8f(v2, f2); b8f(v3, f3);
#pragma unroll
    for (int j = 0; j < 8; j++)
      acc[j] += w0 * f0[j] + w1 * f1[j] + w2 * f2[j] + w3 * f3[j];
  }
  short8 o;
#pragma unroll
  for (int j = 0; j < 8; j++) o[j] = f2b(acc[j]);
  *(short8*)(out + (size_t)(blockIdx.x * 256 + t) * 8) = o;
}

// ---------------------------------------------------------------------------
// Launch
// ---------------------------------------------------------------------------
extern "C" void kernel_launch(void* const* d_in, const int* in_sizes, int n_in,
                              void* d_out, int out_size, void* d_ws, size_t ws_size,
                              hipStream_t stream)
{
  const float* query     = (const float*)d_in[0];
  const float* value     = (const float*)d_in[1];
  const float* query_pos = (const float*)d_in[2];
  const float* ref_pts   = (const float*)d_in[3];
  const float* g1  = (const float*)d_in[6];
  const float* b1  = (const float*)d_in[7];
  const float* Wo  = (const float*)d_in[8];
  const float* bo  = (const float*)d_in[9];
  const float* Wa  = (const float*)d_in[10];
  const float* ba  = (const float*)d_in[11];
  const float* Wv  = (const float*)d_in[12];
  const float* bv  = (const float*)d_in[13];
  const float* Wp  = (const float*)d_in[14];
  const float* bp  = (const float*)d_in[15];
  const float* g2  = (const float*)d_in[16];
  const float* b2  = (const float*)d_in[17];
  const float* Wf1 = (const float*)d_in[18];
  const float* bf1 = (const float*)d_in[19];
  const float* Wf2 = (const float*)d_in[20];
  const float* bf2 = (const float*)d_in[21];

  char* ws = (char*)d_ws;
  short* wt_oa   = (short*)(ws + 0);          // 384x256 bf16
  short* wt_v    = (short*)(ws + 196608);
  short* wt_p    = (short*)(ws + 327680);
  short* wt_f1   = (short*)(ws + 458752);
  short* wt_f2   = (short*)(ws + 983040);
  short* qnb     = (short*)(ws + 1507328);    // 16384x256 bf16 (LN1, no pos)
  short* qa      = (short*)(ws + 18284544);   // 16384x256 bf16 (later q2)
  float* oabuf   = (float*)(ws + 26673152);   // 16384x288 f32 (dead after gather)
  short* vproj   = (short*)(ws + 45547520);   // 12600x256 bf16
  short* sampled = (short*)(ws + 51998720);   // 16384x256 bf16
  float* qbuf    = (float*)(ws + 60387328);   // 16384x256 f32
  short* valbf   = (short*)(ws + 77164544);   // 12672x256 bf16
  short* q2      = qa;                        // reuse (qa dead after oa GEMM)
  short* hidden  = (short*)(ws + 26673152);   // 16384x1024 bf16
  float* outp = (float*)d_out;

  // 1. merged: weight convert + value convert + LN1
  prep_all<<<9057, 256, 0, stream>>>(Wo, Wa, Wv, Wp, Wf1, Wf2,
                                     wt_oa, wt_v, wt_p, wt_f1, wt_f2,
                                     value, valbf, query, query_pos,
                                     g1, b1, qnb, qa);
  // 2. merged GEMMs: oa (768 blocks) + vproj (394 blocks), fullk core
  gemm_oa_v<<<1162, 256, 0, stream>>>(qa, wt_oa, bo, ba, oabuf,
                                      valbf, wt_v, bv, vproj);
  // 3. fused prep+gather -> sampled bf16
  deform_fused<<<2048, 256, 0, stream>>>(vproj, oabuf, ref_pts, sampled);
  // 4. qbuf = sampled@Wp + bp + b2f(qnb) + query; q2 = LN(qbuf)  (fused)
  gemm_wp_ln2<<<512, 256, 0, stream>>>(sampled, wt_p, bp, qnb, query,
                                       g2, b2, qbuf, q2);
  // 5. hidden = gelu(q2 @ Wf1 + bf1) bf16  (fullk, grid (8,256))
  gemm_fullk_k<1><<<dim3(8, 256), 256, 0, stream>>>(q2, wt_f1, bf1, nullptr,
                                                    hidden, 16384, 1024, 1024, 256);
  // 6. out = qbuf + hidden @ Wf2 + bf2  (fullk, K=1024 -> 4 chunks)
  gemm_fullk_k<3><<<dim3(2, 256), 256, 0, stream>>>(hidden, wt_f2, bf2, qbuf,
                                                    outp, 16384, 256, 256, 1024);
}

// Round 14
// 233.666 us; speedup vs baseline: 1.0962x; 1.0962x over previous
//
#include <hip/hip_runtime.h>
#include <math.h>

// ---------------------------------------------------------------------------
// Deformable transformer layer, MI355X round-14:
//  - round-12 structure restored (proven 228 us; round-13 fullk reverted).
//  - NEW 64x64-tile core (16 KB LDS) for Wf1 (10 blocks/CU, LDS-capped) and
//    Wf2 (4 blocks/CU). Fourth application of the blocks/CU lesson.
//  6 dispatches.
// B=2, Nq=8192, C=256, HEADS=8, dh=32, LEVELS=3, POINTS=4, MLP=4
// ---------------------------------------------------------------------------

typedef short short8 __attribute__((ext_vector_type(8)));
typedef short s16x4 __attribute__((ext_vector_type(4)));
typedef __bf16 bf16x8 __attribute__((ext_vector_type(8)));
typedef float f32x4 __attribute__((ext_vector_type(4)));

__device__ __forceinline__ short f2b(float f) {
  unsigned u = __builtin_bit_cast(unsigned, f);
  u += 0x7fffu + ((u >> 16) & 1u);   // RNE to bf16
  return (short)(u >> 16);
}
__device__ __forceinline__ float b2f(short s) {
  unsigned u = ((unsigned)(unsigned short)s) << 16;
  return __builtin_bit_cast(float, u);
}
__device__ __forceinline__ void b8f(short8 s, float* f) {
  const uint4 u = __builtin_bit_cast(uint4, s);
  f[0] = __builtin_bit_cast(float, u.x << 16);
  f[1] = __builtin_bit_cast(float, u.x & 0xffff0000u);
  f[2] = __builtin_bit_cast(float, u.y << 16);
  f[3] = __builtin_bit_cast(float, u.y & 0xffff0000u);
  f[4] = __builtin_bit_cast(float, u.z << 16);
  f[5] = __builtin_bit_cast(float, u.z & 0xffff0000u);
  f[6] = __builtin_bit_cast(float, u.w << 16);
  f[7] = __builtin_bit_cast(float, u.w & 0xffff0000u);
}

__device__ __forceinline__ f32x4 mfma16(short8 a, short8 b, f32x4 c) {
  return __builtin_amdgcn_mfma_f32_16x16x32_bf16(
      __builtin_bit_cast(bf16x8, a), __builtin_bit_cast(bf16x8, b), c, 0, 0, 0);
}

typedef __attribute__((address_space(3))) unsigned int lds_u32;
typedef const __attribute__((address_space(1))) unsigned int glb_u32;
__device__ __forceinline__ void glds16(const void* g, void* l) {
  __builtin_amdgcn_global_load_lds((glb_u32*)g, (lds_u32*)l, 16, 0, 0);
}

__device__ __forceinline__ float gelu1(float v) {
  return 0.5f * v * (1.f + erff(v * 0.70710678118654752f));
}

// ---------------------------------------------------------------------------
// GEMM core 64x128 tile, BK=64, 24 KB LDS (rounds 10-12 proven). For oa_v.
// EPI: 4=oa (bias split 192/96, f32) | 5=bf16+bias
// ---------------------------------------------------------------------------
template <int EPI>
__device__ __forceinline__ void gemm64_core(
    int bx, int by,
    const short* __restrict__ A, const short* __restrict__ Bt,
    const float* __restrict__ bias, const float* __restrict__ bias2,
    void* __restrict__ Cout, int M, int Nreal, int ldc, int K, char* smem)
{
  short* sA = (short*)smem;       // [64][64] shorts (8 KB)
  short* sB = sA + 4096;          // [128][64] shorts (16 KB)
  float* sf = (float*)smem;       // epilogue staging [32][132]

  const int t = threadIdx.x;
  const int wave = t >> 6, lane = t & 63;
  const int quad = lane >> 4, l16 = lane & 15;
  const int wm = (wave & 1) * 32, wn = (wave >> 1) * 64;
  const int m0 = by * 64, n0 = bx * 128;

  f32x4 acc[2][4];
#pragma unroll
  for (int i = 0; i < 2; i++)
#pragma unroll
    for (int j = 0; j < 4; j++) acc[i][j] = (f32x4){0.f, 0.f, 0.f, 0.f};

  const int srow = lane >> 3, pos = lane & 7;
  const int chunk = (pos + srow) & 7;
  const short* gA = A + (size_t)(m0 + wave * 16 + srow) * K + chunk * 8;
  const short* gB = Bt + (size_t)(n0 + wave * 32 + srow) * K + chunk * 8;

  const int nk = K >> 6;
  for (int kt = 0; kt < nk; ++kt) {
    if (kt) __syncthreads();
    const int ko = kt * 64;
#pragma unroll
    for (int g = 0; g < 2; ++g)
      glds16(gA + ko + (size_t)(g * 8) * K, sA + (wave * 16 + g * 8) * 64);
#pragma unroll
    for (int g = 0; g < 4; ++g)
      glds16(gB + ko + (size_t)(g * 8) * K, sB + (wave * 32 + g * 8) * 64);
    __syncthreads();
#pragma unroll
    for (int kk = 0; kk < 2; ++kk) {
      short8 af[2], bf[4];
      const int c = kk * 4 + quad;
#pragma unroll
      for (int i = 0; i < 2; i++) {
        const int lrA = wm + i * 16 + l16;
        af[i] = *(const short8*)&sA[lrA * 64 + ((c - lrA) & 7) * 8];
      }
#pragma unroll
      for (int j = 0; j < 4; j++) {
        const int lrB = wn + j * 16 + l16;
        bf[j] = *(const short8*)&sB[lrB * 64 + ((c - lrB) & 7) * 8];
      }
#pragma unroll
      for (int i = 0; i < 2; i++)
#pragma unroll
        for (int j = 0; j < 4; j++) acc[i][j] = mfma16(bf[j], af[i], acc[i][j]);
    }
  }
  __syncthreads();

#pragma unroll
  for (int b = 0; b < 2; ++b) {
    if (wm == b * 32) {
#pragma unroll
      for (int i = 0; i < 2; ++i) {
        const int rr = i * 16 + l16;
#pragma unroll
        for (int j = 0; j < 4; ++j)
          *(f32x4*)&sf[rr * 132 + wn + quad * 4 + j * 16] = acc[i][j];
      }
    }
    __syncthreads();
#pragma unroll
    for (int r2 = 0; r2 < 4; ++r2) {
      const int fidx = r2 * 1024 + t * 4;
      const int row = fidx >> 7, col = fidx & 127;
      const int gm = m0 + b * 32 + row;
      const int cc = n0 + col;
      if (gm < M && cc < Nreal) {
        const float4 v = *(const float4*)&sf[row * 132 + col];
        float4 bb;
        if (EPI == 4) bb = (cc < 192) ? *(const float4*)(bias + cc)
                                      : *(const float4*)(bias2 + cc - 192);
        else bb = *(const float4*)(bias + cc);
        float v0 = v.x + bb.x, v1 = v.y + bb.y, v2 = v.z + bb.z, v3 = v.w + bb.w;
        if (EPI == 5) {
          s16x4 o; o.x = f2b(v0); o.y = f2b(v1); o.z = f2b(v2); o.w = f2b(v3);
          *(s16x4*)((short*)Cout + (size_t)gm * ldc + cc) = o;
        } else {
          *(float4*)((float*)Cout + (size_t)gm * ldc + cc) =
              make_float4(v0, v1, v2, v3);
        }
      }
    }
    __syncthreads();
  }
}

// Merged: blocks [0,768) -> oa GEMM (EPI4), [768,1162) -> v GEMM (EPI5)
__global__ __launch_bounds__(256) void gemm_oa_v(
    const short* __restrict__ qa, const short* __restrict__ wt_oa,
    const float* __restrict__ bo, const float* __restrict__ ba,
    float* __restrict__ oabuf,
    const short* __restrict__ valbf, const short* __restrict__ wt_v,
    const float* __restrict__ bv, short* __restrict__ vproj)
{
  __shared__ __align__(16) char smem[24576];
  const int idx = blockIdx.x;
  if (idx < 768) {
    gemm64_core<4>(idx % 3, idx / 3, qa, wt_oa, bo, ba,
                   oabuf, 16384, 288, 288, 256, smem);
  } else {
    const int r = idx - 768;
    gemm64_core<5>(r % 2, r / 2, valbf, wt_v, bv, nullptr,
                   vproj, 12600, 256, 256, 256, smem);
  }
}

// ---------------------------------------------------------------------------
// GEMM core 64x64 tile, BK=64, 16 KB LDS -> up to 10 blocks/CU. Wave w:
// rows (w&1)*32..+31, cols (w>>1)*32..+31; acc[2][2]; 8 MFMA vs 4 glds/iter.
// EPI: 1=gelu->bf16 | 3=f32: bias + f32 add1
// ---------------------------------------------------------------------------
template <int EPI>
__global__ __launch_bounds__(256) void gemm44_k(
    const short* __restrict__ A, const short* __restrict__ Bt,
    const float* __restrict__ bias, const float* __restrict__ add1,
    void* __restrict__ Cout, int ldc, int K)
{
  __shared__ __align__(16) char smem[16384];
  short* sA = (short*)smem;       // [64][64] shorts (8 KB)
  short* sB = sA + 4096;          // [64][64] shorts (8 KB)
  float* sf = (float*)smem;       // epilogue staging [32][68] (8.7 KB)

  const int t = threadIdx.x;
  const int wave = t >> 6, lane = t & 63;
  const int quad = lane >> 4, l16 = lane & 15;
  const int wm = (wave & 1) * 32, wn = (wave >> 1) * 32;
  const int m0 = blockIdx.y * 64, n0 = blockIdx.x * 64;

  f32x4 acc[2][2];
#pragma unroll
  for (int i = 0; i < 2; i++)
#pragma unroll
    for (int j = 0; j < 2; j++) acc[i][j] = (f32x4){0.f, 0.f, 0.f, 0.f};

  const int srow = lane >> 3, pos = lane & 7;
  const int chunk = (pos + srow) & 7;
  const short* gA = A + (size_t)(m0 + wave * 16 + srow) * K + chunk * 8;
  const short* gB = Bt + (size_t)(n0 + wave * 16 + srow) * K + chunk * 8;

  const int nk = K >> 6;
  for (int kt = 0; kt < nk; ++kt) {
    if (kt) __syncthreads();
    const int ko = kt * 64;
#pragma unroll
    for (int g = 0; g < 2; ++g) {
      glds16(gA + ko + (size_t)(g * 8) * K, sA + (wave * 16 + g * 8) * 64);
      glds16(gB + ko + (size_t)(g * 8) * K, sB + (wave * 16 + g * 8) * 64);
    }
    __syncthreads();
#pragma unroll
    for (int kk = 0; kk < 2; ++kk) {
      short8 af[2], bf[2];
      const int c = kk * 4 + quad;
#pragma unroll
      for (int i = 0; i < 2; i++) {
        const int lrA = wm + i * 16 + l16;
        af[i] = *(const short8*)&sA[lrA * 64 + ((c - lrA) & 7) * 8];
        const int lrB = wn + i * 16 + l16;
        bf[i] = *(const short8*)&sB[lrB * 64 + ((c - lrB) & 7) * 8];
      }
#pragma unroll
      for (int i = 0; i < 2; i++)
#pragma unroll
        for (int j = 0; j < 2; j++) acc[i][j] = mfma16(bf[j], af[i], acc[i][j]);
    }
  }
  __syncthreads();

  // Epilogue: 2 bands of 32 rows x 64 cols via sf[32][68].
#pragma unroll
  for (int b = 0; b < 2; ++b) {
    if (wm == b * 32) {
#pragma unroll
      for (int i = 0; i < 2; ++i) {
        const int rr = i * 16 + l16;
#pragma unroll
        for (int j = 0; j < 2; ++j)
          *(f32x4*)&sf[rr * 68 + wn + j * 16 + quad * 4] = acc[i][j];
      }
    }
    __syncthreads();
#pragma unroll
    for (int r2 = 0; r2 < 2; ++r2) {
      const int fidx = r2 * 1024 + t * 4;
      const int row = fidx >> 6, col = fidx & 63;
      const int gm = m0 + b * 32 + row;
      const int cc = n0 + col;
      const float4 v = *(const float4*)&sf[row * 68 + col];
      const float4 bb = *(const float4*)(bias + cc);
      float v0 = v.x + bb.x, v1 = v.y + bb.y, v2 = v.z + bb.z, v3 = v.w + bb.w;
      if (EPI == 1) {
        v0 = gelu1(v0); v1 = gelu1(v1); v2 = gelu1(v2); v3 = gelu1(v3);
        s16x4 o; o.x = f2b(v0); o.y = f2b(v1); o.z = f2b(v2); o.w = f2b(v3);
        *(s16x4*)((short*)Cout + (size_t)gm * ldc + cc) = o;
      } else {
        const float4 a1 = *(const float4*)(add1 + (size_t)gm * ldc + cc);
        *(float4*)((float*)Cout + (size_t)gm * ldc + cc) =
            make_float4(v0 + a1.x, v1 + a1.y, v2 + a1.z, v3 + a1.w);
      }
    }
    __syncthreads();
  }
}

// ---------------------------------------------------------------------------
// gemm_wp_ln2: 32x256 tile, block owns COMPLETE rows (round-12, proven).
// qbuf = acc + bp + b2f(qnb) + query; q2 = LN(qbuf; g2,b2) fused epilogue.
// ---------------------------------------------------------------------------
__global__ __launch_bounds__(256) void gemm_wp_ln2(
    const short* __restrict__ A, const short* __restrict__ Bt,
    const float* __restrict__ bias,
    const short* __restrict__ qnb, const float* __restrict__ query,
    const float* __restrict__ g2, const float* __restrict__ b2v,
    float* __restrict__ qbuf, short* __restrict__ q2)
{
  __shared__ __align__(16) char smem[36864];
  short* sA = (short*)smem;        // [32][64] shorts (4 KB)
  short* sB = sA + 2048;           // [256][64] shorts (32 KB)
  float* sf = (float*)smem;        // epilogue staging [32][260]

  const int t = threadIdx.x;
  const int wave = t >> 6, lane = t & 63;
  const int quad = lane >> 4, l16 = lane & 15;
  const int wm = (wave & 1) * 16, wn = (wave >> 1) * 128;
  const int m0 = blockIdx.x * 32;
  const int K = 256;

  f32x4 acc[8];
#pragma unroll
  for (int j = 0; j < 8; j++) acc[j] = (f32x4){0.f, 0.f, 0.f, 0.f};

  const int srow = lane >> 3, pos = lane & 7;
  const int chunk = (pos + srow) & 7;
  const short* gA = A + (size_t)(m0 + wave * 8 + srow) * K + chunk * 8;
  const short* gB = Bt + (size_t)(wave * 64 + srow) * K + chunk * 8;

  for (int kt = 0; kt < 4; ++kt) {
    if (kt) __syncthreads();
    const int ko = kt * 64;
    glds16(gA + ko, sA + (wave * 8) * 64);
#pragma unroll
    for (int g = 0; g < 8; ++g)
      glds16(gB + ko + (size_t)(g * 8) * K, sB + (wave * 64 + g * 8) * 64);
    __syncthreads();
#pragma unroll
    for (int kk = 0; kk < 2; ++kk) {
      const int c = kk * 4 + quad;
      const int lrA = wm + l16;
      const short8 af = *(const short8*)&sA[lrA * 64 + ((c - lrA) & 7) * 8];
      short8 bf[8];
#pragma unroll
      for (int j = 0; j < 8; j++) {
        const int lrB = wn + j * 16 + l16;
        bf[j] = *(const short8*)&sB[lrB * 64 + ((c - lrB) & 7) * 8];
      }
#pragma unroll
      for (int j = 0; j < 8; j++) acc[j] = mfma16(bf[j], af, acc[j]);
    }
  }
  __syncthreads();

#pragma unroll
  for (int j = 0; j < 8; j++)
    *(f32x4*)&sf[(wm + l16) * 260 + wn + j * 16 + quad * 4] = acc[j];
  __syncthreads();

  const float4 bb   = *(const float4*)(bias + lane * 4);
  const float4 gv   = *(const float4*)(g2 + lane * 4);
  const float4 b2f4 = *(const float4*)(b2v + lane * 4);
#pragma unroll
  for (int rr = 0; rr < 8; ++rr) {
    const int row = wave * 8 + rr;
    const int gm = m0 + row;
    const float4 a = *(const float4*)&sf[row * 260 + lane * 4];
    const s16x4 qn = *(const s16x4*)(qnb + (size_t)gm * 256 + lane * 4);
    const float4 qv = *(const float4*)(query + (size_t)gm * 256 + lane * 4);
    float q0 = a.x + bb.x + b2f(qn.x) + qv.x;
    float q1 = a.y + bb.y + b2f(qn.y) + qv.y;
    float q2f = a.z + bb.z + b2f(qn.z) + qv.z;
    float q3 = a.w + bb.w + b2f(qn.w) + qv.w;
    float s = q0 + q1 + q2f + q3;
#pragma unroll
    for (int o = 32; o; o >>= 1) s += __shfl_xor(s, o);
    const float mean = s * (1.f / 256.f);
    const float d0 = q0 - mean, d1 = q1 - mean, d2 = q2f - mean, d3 = q3 - mean;
    float ss = d0 * d0 + d1 * d1 + d2 * d2 + d3 * d3;
#pragma unroll
    for (int o = 32; o; o >>= 1) ss += __shfl_xor(ss, o);
    const float inv = rsqrtf(ss * (1.f / 256.f) + 1e-5f);
    *(float4*)(qbuf + (size_t)gm * 256 + lane * 4) = make_float4(q0, q1, q2f, q3);
    s16x4 o2;
    o2.x = f2b(d0 * inv * gv.x + b2f4.x);
    o2.y = f2b(d1 * inv * gv.y + b2f4.y);
    o2.z = f2b(d2 * inv * gv.z + b2f4.z);
    o2.w = f2b(d3 * inv * gv.w + b2f4.w);
    *(s16x4*)(q2 + (size_t)gm * 256 + lane * 4) = o2;
  }
}

// ---------------------------------------------------------------------------
// prep_all: merged wconvert (1792 blocks) + vconvert (3169) + LN1 (4096).
// ---------------------------------------------------------------------------
__global__ __launch_bounds__(256) void prep_all(
    const float* __restrict__ Wo, const float* __restrict__ Wa,
    const float* __restrict__ Wv, const float* __restrict__ Wp,
    const float* __restrict__ Wf1, const float* __restrict__ Wf2,
    short* __restrict__ t_oa, short* __restrict__ t_v, short* __restrict__ t_p,
    short* __restrict__ t_f1, short* __restrict__ t_f2,
    const float* __restrict__ value, short* __restrict__ valbf,
    const float* __restrict__ query, const float* __restrict__ query_pos,
    const float* __restrict__ g1, const float* __restrict__ b1,
    short* __restrict__ qnb, short* __restrict__ qa)
{
  __shared__ float tile[32][33];
  const int t = threadIdx.x;
  const int blk = blockIdx.x;

  if (blk < 1792) {
    const int bxa = blk & 255, bya = blk >> 8;
    int K, N, noff; const float* src; short* dst;
    switch (bya) {
      case 0: src = Wo;      dst = t_oa; K = 256;  N = 192;  noff = 0;   break;
      case 1: src = Wa;      dst = t_oa; K = 256;  N = 96;   noff = 192; break;
      case 2: src = nullptr; dst = t_oa; K = 256;  N = 96;   noff = 288; break;
      case 3: src = Wv;      dst = t_v;  K = 256;  N = 256;  noff = 0;   break;
      case 4: src = Wp;      dst = t_p;  K = 256;  N = 256;  noff = 0;   break;
      case 5: src = Wf1;     dst = t_f1; K = 256;  N = 1024; noff = 0;   break;
      default: src = Wf2;    dst = t_f2; K = 1024; N = 256;  noff = 0;   break;
    }
    const int tilesK = K >> 5;
    const int nt = tilesK * (N >> 5);
    if (bxa >= nt) return;
    const int tk = bxa % tilesK, tn = bxa / tilesK;
    const int k0 = tk * 32, n0 = tn * 32;
    const int r = t >> 3, c4 = (t & 7) * 4;
    float4 v = make_float4(0.f, 0.f, 0.f, 0.f);
    if (src) v = *(const float4*)(src + (size_t)(k0 + r) * N + n0 + c4);
    tile[r][c4] = v.x; tile[r][c4 + 1] = v.y; tile[r][c4 + 2] = v.z; tile[r][c4 + 3] = v.w;
    __syncthreads();
    const int nn = t >> 3, kc = (t & 7) * 4;
    s16x4 o;
    o.x = f2b(tile[kc][nn]); o.y = f2b(tile[kc + 1][nn]);
    o.z = f2b(tile[kc + 2][nn]); o.w = f2b(tile[kc + 3][nn]);
    *(s16x4*)(dst + (size_t)(noff + n0 + nn) * K + k0 + kc) = o;
  } else if (blk < 1792 + 3169) {
    const int i = ((blk - 1792) * 256 + t) * 4;
    if (i >= 12672 * 256) return;
    s16x4 o = (s16x4){0, 0, 0, 0};
    if (i < 12600 * 256) {
      float4 v = *(const float4*)(value + i);
      o.x = f2b(v.x); o.y = f2b(v.y); o.z = f2b(v.z); o.w = f2b(v.w);
    }
    *(s16x4*)(valbf + i) = o;
  } else {
    const int row  = (blk - 4961) * 4 + (t >> 6);
    const int lane = t & 63;
    const float4 v = ((const float4*)(query + (size_t)row * 256))[lane];
    float s = v.x + v.y + v.z + v.w;
#pragma unroll
    for (int o = 32; o; o >>= 1) s += __shfl_xor(s, o);
    const float mean = s * (1.f / 256.f);
    const float dx = v.x - mean, dy = v.y - mean, dz = v.z - mean, dw = v.w - mean;
    float s2 = dx * dx + dy * dy + dz * dz + dw * dw;
#pragma unroll
    for (int o = 32; o; o >>= 1) s2 += __shfl_xor(s2, o);
    const float inv = rsqrtf(s2 * (1.f / 256.f) + 1e-5f);
    const float4 gv = ((const float4*)g1)[lane];
    const float4 bv = ((const float4*)b1)[lane];
    const float4 o1 = make_float4(dx * inv * gv.x + bv.x, dy * inv * gv.y + bv.y,
                                  dz * inv * gv.z + bv.z, dw * inv * gv.w + bv.w);
    s16x4 ob; ob.x = f2b(o1.x); ob.y = f2b(o1.y); ob.z = f2b(o1.z); ob.w = f2b(o1.w);
    ((s16x4*)(qnb + (size_t)row * 256))[lane] = ob;
    const float4 pv = ((const float4*)(query_pos + (size_t)row * 256))[lane];
    s16x4 op;
    op.x = f2b(o1.x + pv.x); op.y = f2b(o1.y + pv.y);
    op.z = f2b(o1.z + pv.z); op.w = f2b(o1.w + pv.w);
    ((s16x4*)(qa + (size_t)row * 256))[lane] = op;
  }
}

// ---------------------------------------------------------------------------
// deform_fused: block = 8 rows. Phase 1 (64 threads): softmax + bilinear
// setup -> LDS tables. Phase 2 (256 threads): pure gather+FMA.
// ---------------------------------------------------------------------------
__global__ __launch_bounds__(256) void deform_fused(
    const short* __restrict__ vproj, const float* __restrict__ oa,
    const float* __restrict__ refp, short* __restrict__ out)
{
  __shared__ int4 sIdx[768];
  __shared__ s16x4 sW[768];
  const int t = threadIdx.x;

  if (t < 64) {
    const int row = blockIdx.x * 8 + (t >> 3), h = t & 7;
    const float* oarow = oa + (size_t)row * 288;
    float off[24];
    const float4* op = (const float4*)(oarow + h * 24);
#pragma unroll
    for (int i = 0; i < 6; i++) {
      const float4 v = op[i];
      off[i * 4] = v.x; off[i * 4 + 1] = v.y; off[i * 4 + 2] = v.z; off[i * 4 + 3] = v.w;
    }
    float lg[12];
    const float4* ap = (const float4*)(oarow + 192 + h * 12);
#pragma unroll
    for (int i = 0; i < 3; i++) {
      const float4 v = ap[i];
      lg[i * 4] = v.x; lg[i * 4 + 1] = v.y; lg[i * 4 + 2] = v.z; lg[i * 4 + 3] = v.w;
    }
    const float* rp = refp + (size_t)row * 6;
    const float Rx[3] = {rp[0], rp[2], rp[4]}, Ry[3] = {rp[1], rp[3], rp[5]};
    float mx = lg[0];
#pragma unroll
    for (int i = 1; i < 12; i++) mx = fmaxf(mx, lg[i]);
    float sum = 0.f;
#pragma unroll
    for (int i = 0; i < 12; i++) { lg[i] = __expf(lg[i] - mx); sum += lg[i]; }
    const float inv = 1.f / sum;
    const int b = row >> 13;
    const int Hs[3] = {60, 30, 15}, Ws[3] = {80, 40, 20}, St[3] = {0, 4800, 6000};
#pragma unroll
    for (int p = 0; p < 12; p++) {
      const int l = p >> 2;
      const int W = Ws[l], H = Hs[l];
      const float gx = Rx[l] * W + off[p * 2]     - 0.5f;
      const float gy = Ry[l] * H + off[p * 2 + 1] - 0.5f;
      const float x0f = floorf(gx), y0f = floorf(gy);
      const float wx = gx - x0f, wy = gy - y0f;
      const int x0 = (int)x0f, y0 = (int)y0f;
      const float aw = lg[p] * inv;
      float cw[4] = {(1.f - wx) * (1.f - wy), wx * (1.f - wy),
                     (1.f - wx) * wy, wx * wy};
      const int base = b * 6300 + St[l];
      int ci[4];
#pragma unroll
      for (int k = 0; k < 4; k++) {
        const int xx = x0 + (k & 1), yy = y0 + (k >> 1);
        const bool valid = (xx >= 0) & (xx < W) & (yy >= 0) & (yy < H);
        const int xc = min(max(xx, 0), W - 1);
        const int yc = min(max(yy, 0), H - 1);
        ci[k] = ((base + yc * W + xc) << 8) + h * 32;
        cw[k] = valid ? cw[k] * aw : 0.f;
      }
      sIdx[t * 12 + p] = make_int4(ci[0], ci[1], ci[2], ci[3]);
      s16x4 wv; wv.x = f2b(cw[0]); wv.y = f2b(cw[1]); wv.z = f2b(cw[2]); wv.w = f2b(cw[3]);
      sW[t * 12 + p] = wv;
    }
  }
  __syncthreads();

  const int lu = t >> 2, c4 = (t & 3) * 8;
  float acc[8];
#pragma unroll
  for (int i = 0; i < 8; i++) acc[i] = 0.f;
#pragma unroll 2
  for (int p = 0; p < 12; p++) {
    const int4 idx = sIdx[lu * 12 + p];
    const s16x4 wb = sW[lu * 12 + p];
    const float w0 = b2f(wb.x), w1 = b2f(wb.y), w2 = b2f(wb.z), w3 = b2f(wb.w);
    const short8 v0 = *(const short8*)(vproj + idx.x + c4);
    const short8 v1 = *(const short8*)(vproj + idx.y + c4);
    const short8 v2 = *(const short8*)(vproj + idx.z + c4);
    const short8 v3 = *(const short8*)(vproj + idx.w + c4);
    float f0[8], f1[8], f2[8], f3[8];
    b8f(v0, f0); b8f(v1, f1); b8f(v2, f2); b8f(v3, f3);
#pragma unroll
    for (int j = 0; j < 8; j++)
      acc[j] += w0 * f0[j] + w1 * f1[j] + w2 * f2[j] + w3 * f3[j];
  }
  short8 o;
#pragma unroll
  for (int j = 0; j < 8; j++) o[j] = f2b(acc[j]);
  *(short8*)(out + (size_t)(blockIdx.x * 256 + t) * 8) = o;
}

// ---------------------------------------------------------------------------
// Launch
// ---------------------------------------------------------------------------
extern "C" void kernel_launch(void* const* d_in, const int* in_sizes, int n_in,
                              void* d_out, int out_size, void* d_ws, size_t ws_size,
                              hipStream_t stream)
{
  const float* query     = (const float*)d_in[0];
  const float* value     = (const float*)d_in[1];
  const float* query_pos = (const float*)d_in[2];
  const float* ref_pts   = (const float*)d_in[3];
  const float* g1  = (const float*)d_in[6];
  const float* b1  = (const float*)d_in[7];
  const float* Wo  = (const float*)d_in[8];
  const float* bo  = (const float*)d_in[9];
  const float* Wa  = (const float*)d_in[10];
  const float* ba  = (const float*)d_in[11];
  const float* Wv  = (const float*)d_in[12];
  const float* bv  = (const float*)d_in[13];
  const float* Wp  = (const float*)d_in[14];
  const float* bp  = (const float*)d_in[15];
  const float* g2  = (const float*)d_in[16];
  const float* b2  = (const float*)d_in[17];
  const float* Wf1 = (const float*)d_in[18];
  const float* bf1 = (const float*)d_in[19];
  const float* Wf2 = (const float*)d_in[20];
  const float* bf2 = (const float*)d_in[21];

  char* ws = (char*)d_ws;
  short* wt_oa   = (short*)(ws + 0);          // 384x256 bf16
  short* wt_v    = (short*)(ws + 196608);
  short* wt_p    = (short*)(ws + 327680);
  short* wt_f1   = (short*)(ws + 458752);
  short* wt_f2   = (short*)(ws + 983040);
  short* qnb     = (short*)(ws + 1507328);    // 16384x256 bf16 (LN1, no pos)
  short* qa      = (short*)(ws + 18284544);   // 16384x256 bf16 (later q2)
  float* oabuf   = (float*)(ws + 26673152);   // 16384x288 f32 (dead after gather)
  short* vproj   = (short*)(ws + 45547520);   // 12600x256 bf16
  short* sampled = (short*)(ws + 51998720);   // 16384x256 bf16
  float* qbuf    = (float*)(ws + 60387328);   // 16384x256 f32
  short* valbf   = (short*)(ws + 77164544);   // 12672x256 bf16
  short* q2      = qa;                        // reuse (qa dead after oa GEMM)
  short* hidden  = (short*)(ws + 26673152);   // 16384x1024 bf16
  float* outp = (float*)d_out;

  // 1. merged: weight convert + value convert + LN1
  prep_all<<<9057, 256, 0, stream>>>(Wo, Wa, Wv, Wp, Wf1, Wf2,
                                     wt_oa, wt_v, wt_p, wt_f1, wt_f2,
                                     value, valbf, query, query_pos,
                                     g1, b1, qnb, qa);
  // 2. merged GEMMs: oa (768 blocks) + vproj (394 blocks), 64x128 core
  gemm_oa_v<<<1162, 256, 0, stream>>>(qa, wt_oa, bo, ba, oabuf,
                                      valbf, wt_v, bv, vproj);
  // 3. fused prep+gather -> sampled bf16
  deform_fused<<<2048, 256, 0, stream>>>(vproj, oabuf, ref_pts, sampled);
  // 4. qbuf = sampled@Wp + bp + b2f(qnb) + query; q2 = LN(qbuf)  (fused)
  gemm_wp_ln2<<<512, 256, 0, stream>>>(sampled, wt_p, bp, qnb, query,
                                       g2, b2, qbuf, q2);
  // 5. hidden = gelu(q2 @ Wf1 + bf1) bf16  (64x64 tile, 4096 blocks, 10/CU)
  gemm44_k<1><<<dim3(16, 256), 256, 0, stream>>>(q2, wt_f1, bf1, nullptr,
                                                 hidden, 1024, 256);
  // 6. out = qbuf + hidden @ Wf2 + bf2  (64x64 tile, 1024 blocks, K=1024)
  gemm44_k<3><<<dim3(4, 256), 256, 0, stream>>>(hidden, wt_f2, bf2, qbuf,
                                                outp, 256, 1024);
}

// Round 15
// 225.463 us; speedup vs baseline: 1.1361x; 1.0364x over previous
//
#include <hip/hip_runtime.h>
#include <math.h>

// ---------------------------------------------------------------------------
// Deformable transformer layer, MI355X round-15:
//  - exact round-12 structure (proven best, 228 us); round-13/14 tile
//    experiments reverted (64x128 @ 24 KB is the bracketed optimum).
//  - NEW: oabuf in bf16 (halves the oa write + deform read round-trip).
//  6 dispatches.
// B=2, Nq=8192, C=256, HEADS=8, dh=32, LEVELS=3, POINTS=4, MLP=4
// ---------------------------------------------------------------------------

typedef short short8 __attribute__((ext_vector_type(8)));
typedef short s16x4 __attribute__((ext_vector_type(4)));
typedef __bf16 bf16x8 __attribute__((ext_vector_type(8)));
typedef float f32x4 __attribute__((ext_vector_type(4)));

__device__ __forceinline__ short f2b(float f) {
  unsigned u = __builtin_bit_cast(unsigned, f);
  u += 0x7fffu + ((u >> 16) & 1u);   // RNE to bf16
  return (short)(u >> 16);
}
__device__ __forceinline__ float b2f(short s) {
  unsigned u = ((unsigned)(unsigned short)s) << 16;
  return __builtin_bit_cast(float, u);
}
__device__ __forceinline__ void b8f(short8 s, float* f) {
  const uint4 u = __builtin_bit_cast(uint4, s);
  f[0] = __builtin_bit_cast(float, u.x << 16);
  f[1] = __builtin_bit_cast(float, u.x & 0xffff0000u);
  f[2] = __builtin_bit_cast(float, u.y << 16);
  f[3] = __builtin_bit_cast(float, u.y & 0xffff0000u);
  f[4] = __builtin_bit_cast(float, u.z << 16);
  f[5] = __builtin_bit_cast(float, u.z & 0xffff0000u);
  f[6] = __builtin_bit_cast(float, u.w << 16);
  f[7] = __builtin_bit_cast(float, u.w & 0xffff0000u);
}

__device__ __forceinline__ f32x4 mfma16(short8 a, short8 b, f32x4 c) {
  return __builtin_amdgcn_mfma_f32_16x16x32_bf16(
      __builtin_bit_cast(bf16x8, a), __builtin_bit_cast(bf16x8, b), c, 0, 0, 0);
}

typedef __attribute__((address_space(3))) unsigned int lds_u32;
typedef const __attribute__((address_space(1))) unsigned int glb_u32;
__device__ __forceinline__ void glds16(const void* g, void* l) {
  __builtin_amdgcn_global_load_lds((glb_u32*)g, (lds_u32*)l, 16, 0, 0);
}

__device__ __forceinline__ float gelu1(float v) {
  return 0.5f * v * (1.f + erff(v * 0.70710678118654752f));
}

// ---------------------------------------------------------------------------
// GEMM core 64x128 tile, BK=64, 24 KB LDS (rounds 10-12 proven optimum).
// EPI: 1=gelu->bf16 | 3=f32: bias+f32 add1 | 4=oa (bias split 192/96, bf16
//      out) | 5=bf16+bias
// ---------------------------------------------------------------------------
template <int EPI>
__device__ __forceinline__ void gemm64_core(
    int bx, int by,
    const short* __restrict__ A, const short* __restrict__ Bt,
    const float* __restrict__ bias, const float* __restrict__ bias2,
    const void* __restrict__ add1,
    void* __restrict__ Cout, int M, int Nreal, int ldc, int K, char* smem)
{
  short* sA = (short*)smem;       // [64][64] shorts (8 KB)
  short* sB = sA + 4096;          // [128][64] shorts (16 KB)
  float* sf = (float*)smem;       // epilogue staging [32][132]

  const int t = threadIdx.x;
  const int wave = t >> 6, lane = t & 63;
  const int quad = lane >> 4, l16 = lane & 15;
  const int wm = (wave & 1) * 32, wn = (wave >> 1) * 64;
  const int m0 = by * 64, n0 = bx * 128;

  f32x4 acc[2][4];
#pragma unroll
  for (int i = 0; i < 2; i++)
#pragma unroll
    for (int j = 0; j < 4; j++) acc[i][j] = (f32x4){0.f, 0.f, 0.f, 0.f};

  const int srow = lane >> 3, pos = lane & 7;
  const int chunk = (pos + srow) & 7;
  const short* gA = A + (size_t)(m0 + wave * 16 + srow) * K + chunk * 8;
  const short* gB = Bt + (size_t)(n0 + wave * 32 + srow) * K + chunk * 8;

  const int nk = K >> 6;
  for (int kt = 0; kt < nk; ++kt) {
    if (kt) __syncthreads();
    const int ko = kt * 64;
#pragma unroll
    for (int g = 0; g < 2; ++g)
      glds16(gA + ko + (size_t)(g * 8) * K, sA + (wave * 16 + g * 8) * 64);
#pragma unroll
    for (int g = 0; g < 4; ++g)
      glds16(gB + ko + (size_t)(g * 8) * K, sB + (wave * 32 + g * 8) * 64);
    __syncthreads();
#pragma unroll
    for (int kk = 0; kk < 2; ++kk) {
      short8 af[2], bf[4];
      const int c = kk * 4 + quad;
#pragma unroll
      for (int i = 0; i < 2; i++) {
        const int lrA = wm + i * 16 + l16;
        af[i] = *(const short8*)&sA[lrA * 64 + ((c - lrA) & 7) * 8];
      }
#pragma unroll
      for (int j = 0; j < 4; j++) {
        const int lrB = wn + j * 16 + l16;
        bf[j] = *(const short8*)&sB[lrB * 64 + ((c - lrB) & 7) * 8];
      }
#pragma unroll
      for (int i = 0; i < 2; i++)
#pragma unroll
        for (int j = 0; j < 4; j++) acc[i][j] = mfma16(bf[j], af[i], acc[i][j]);
    }
  }
  __syncthreads();

  // Epilogue: 2 bands of 32 rows x 128 cols, coalesced full-line stores.
#pragma unroll
  for (int b = 0; b < 2; ++b) {
    if (wm == b * 32) {
#pragma unroll
      for (int i = 0; i < 2; ++i) {
        const int rr = i * 16 + l16;
#pragma unroll
        for (int j = 0; j < 4; ++j)
          *(f32x4*)&sf[rr * 132 + wn + quad * 4 + j * 16] = acc[i][j];
      }
    }
    __syncthreads();
#pragma unroll
    for (int r2 = 0; r2 < 4; ++r2) {
      const int fidx = r2 * 1024 + t * 4;
      const int row = fidx >> 7, col = fidx & 127;
      const int gm = m0 + b * 32 + row;
      const int cc = n0 + col;
      if (gm < M && cc < Nreal) {
        const float4 v = *(const float4*)&sf[row * 132 + col];
        float4 bb;
        if (EPI == 4) bb = (cc < 192) ? *(const float4*)(bias + cc)
                                      : *(const float4*)(bias2 + cc - 192);
        else bb = *(const float4*)(bias + cc);
        float v0 = v.x + bb.x, v1 = v.y + bb.y, v2 = v.z + bb.z, v3 = v.w + bb.w;
        if (EPI == 1) {
          v0 = gelu1(v0); v1 = gelu1(v1); v2 = gelu1(v2); v3 = gelu1(v3);
          s16x4 o; o.x = f2b(v0); o.y = f2b(v1); o.z = f2b(v2); o.w = f2b(v3);
          *(s16x4*)((short*)Cout + (size_t)gm * ldc + cc) = o;
        } else if (EPI == 5 || EPI == 4) {
          s16x4 o; o.x = f2b(v0); o.y = f2b(v1); o.z = f2b(v2); o.w = f2b(v3);
          *(s16x4*)((short*)Cout + (size_t)gm * ldc + cc) = o;
        } else {
          if (EPI == 3) {
            const float4 a1 = *(const float4*)((const float*)add1 + (size_t)gm * ldc + cc);
            v0 += a1.x; v1 += a1.y; v2 += a1.z; v3 += a1.w;
          }
          *(float4*)((float*)Cout + (size_t)gm * ldc + cc) =
              make_float4(v0, v1, v2, v3);
        }
      }
    }
    __syncthreads();
  }
}

template <int EPI>
__global__ __launch_bounds__(256) void gemm64_k(
    const short* __restrict__ A, const short* __restrict__ Bt,
    const float* __restrict__ bias, const void* __restrict__ add1,
    void* __restrict__ Cout, int M, int Nreal, int ldc, int K)
{
  __shared__ __align__(16) char smem[24576];
  gemm64_core<EPI>(blockIdx.x, blockIdx.y, A, Bt, bias, nullptr, add1,
                   Cout, M, Nreal, ldc, K, smem);
}

// Merged: blocks [0,768) -> oa GEMM (EPI4, bf16 out), [768,1162) -> v (EPI5)
__global__ __launch_bounds__(256) void gemm_oa_v(
    const short* __restrict__ qa, const short* __restrict__ wt_oa,
    const float* __restrict__ bo, const float* __restrict__ ba,
    short* __restrict__ oabuf,
    const short* __restrict__ valbf, const short* __restrict__ wt_v,
    const float* __restrict__ bv, short* __restrict__ vproj)
{
  __shared__ __align__(16) char smem[24576];
  const int idx = blockIdx.x;
  if (idx < 768) {
    gemm64_core<4>(idx % 3, idx / 3, qa, wt_oa, bo, ba, nullptr,
                   oabuf, 16384, 288, 288, 256, smem);
  } else {
    const int r = idx - 768;
    gemm64_core<5>(r % 2, r / 2, valbf, wt_v, bv, nullptr, nullptr,
                   vproj, 12600, 256, 256, 256, smem);
  }
}

// ---------------------------------------------------------------------------
// gemm_wp_ln2: 32x256 tile, block owns COMPLETE rows (round-12, proven).
// qbuf = acc + bp + b2f(qnb) + query; q2 = LN(qbuf; g2,b2) fused epilogue.
// ---------------------------------------------------------------------------
__global__ __launch_bounds__(256) void gemm_wp_ln2(
    const short* __restrict__ A, const short* __restrict__ Bt,
    const float* __restrict__ bias,
    const short* __restrict__ qnb, const float* __restrict__ query,
    const float* __restrict__ g2, const float* __restrict__ b2v,
    float* __restrict__ qbuf, short* __restrict__ q2)
{
  __shared__ __align__(16) char smem[36864];
  short* sA = (short*)smem;        // [32][64] shorts (4 KB)
  short* sB = sA + 2048;           // [256][64] shorts (32 KB)
  float* sf = (float*)smem;        // epilogue staging [32][260]

  const int t = threadIdx.x;
  const int wave = t >> 6, lane = t & 63;
  const int quad = lane >> 4, l16 = lane & 15;
  const int wm = (wave & 1) * 16, wn = (wave >> 1) * 128;
  const int m0 = blockIdx.x * 32;
  const int K = 256;

  f32x4 acc[8];
#pragma unroll
  for (int j = 0; j < 8; j++) acc[j] = (f32x4){0.f, 0.f, 0.f, 0.f};

  const int srow = lane >> 3, pos = lane & 7;
  const int chunk = (pos + srow) & 7;
  const short* gA = A + (size_t)(m0 + wave * 8 + srow) * K + chunk * 8;
  const short* gB = Bt + (size_t)(wave * 64 + srow) * K + chunk * 8;

  for (int kt = 0; kt < 4; ++kt) {
    if (kt) __syncthreads();
    const int ko = kt * 64;
    glds16(gA + ko, sA + (wave * 8) * 64);
#pragma unroll
    for (int g = 0; g < 8; ++g)
      glds16(gB + ko + (size_t)(g * 8) * K, sB + (wave * 64 + g * 8) * 64);
    __syncthreads();
#pragma unroll
    for (int kk = 0; kk < 2; ++kk) {
      const int c = kk * 4 + quad;
      const int lrA = wm + l16;
      const short8 af = *(const short8*)&sA[lrA * 64 + ((c - lrA) & 7) * 8];
      short8 bf[8];
#pragma unroll
      for (int j = 0; j < 8; j++) {
        const int lrB = wn + j * 16 + l16;
        bf[j] = *(const short8*)&sB[lrB * 64 + ((c - lrB) & 7) * 8];
      }
#pragma unroll
      for (int j = 0; j < 8; j++) acc[j] = mfma16(bf[j], af, acc[j]);
    }
  }
  __syncthreads();

#pragma unroll
  for (int j = 0; j < 8; j++)
    *(f32x4*)&sf[(wm + l16) * 260 + wn + j * 16 + quad * 4] = acc[j];
  __syncthreads();

  const float4 bb   = *(const float4*)(bias + lane * 4);
  const float4 gv   = *(const float4*)(g2 + lane * 4);
  const float4 b2f4 = *(const float4*)(b2v + lane * 4);
#pragma unroll
  for (int rr = 0; rr < 8; ++rr) {
    const int row = wave * 8 + rr;
    const int gm = m0 + row;
    const float4 a = *(const float4*)&sf[row * 260 + lane * 4];
    const s16x4 qn = *(const s16x4*)(qnb + (size_t)gm * 256 + lane * 4);
    const float4 qv = *(const float4*)(query + (size_t)gm * 256 + lane * 4);
    float q0 = a.x + bb.x + b2f(qn.x) + qv.x;
    float q1 = a.y + bb.y + b2f(qn.y) + qv.y;
    float q2f = a.z + bb.z + b2f(qn.z) + qv.z;
    float q3 = a.w + bb.w + b2f(qn.w) + qv.w;
    float s = q0 + q1 + q2f + q3;
#pragma unroll
    for (int o = 32; o; o >>= 1) s += __shfl_xor(s, o);
    const float mean = s * (1.f / 256.f);
    const float d0 = q0 - mean, d1 = q1 - mean, d2 = q2f - mean, d3 = q3 - mean;
    float ss = d0 * d0 + d1 * d1 + d2 * d2 + d3 * d3;
#pragma unroll
    for (int o = 32; o; o >>= 1) ss += __shfl_xor(ss, o);
    const float inv = rsqrtf(ss * (1.f / 256.f) + 1e-5f);
    *(float4*)(qbuf + (size_t)gm * 256 + lane * 4) = make_float4(q0, q1, q2f, q3);
    s16x4 o2;
    o2.x = f2b(d0 * inv * gv.x + b2f4.x);
    o2.y = f2b(d1 * inv * gv.y + b2f4.y);
    o2.z = f2b(d2 * inv * gv.z + b2f4.z);
    o2.w = f2b(d3 * inv * gv.w + b2f4.w);
    *(s16x4*)(q2 + (size_t)gm * 256 + lane * 4) = o2;
  }
}

// ---------------------------------------------------------------------------
// prep_all: merged wconvert (1792 blocks) + vconvert (3169) + LN1 (4096).
// ---------------------------------------------------------------------------
__global__ __launch_bounds__(256) void prep_all(
    const float* __restrict__ Wo, const float* __restrict__ Wa,
    const float* __restrict__ Wv, const float* __restrict__ Wp,
    const float* __restrict__ Wf1, const float* __restrict__ Wf2,
    short* __restrict__ t_oa, short* __restrict__ t_v, short* __restrict__ t_p,
    short* __restrict__ t_f1, short* __restrict__ t_f2,
    const float* __restrict__ value, short* __restrict__ valbf,
    const float* __restrict__ query, const float* __restrict__ query_pos,
    const float* __restrict__ g1, const float* __restrict__ b1,
    short* __restrict__ qnb, short* __restrict__ qa)
{
  __shared__ float tile[32][33];
  const int t = threadIdx.x;
  const int blk = blockIdx.x;

  if (blk < 1792) {
    const int bxa = blk & 255, bya = blk >> 8;
    int K, N, noff; const float* src; short* dst;
    switch (bya) {
      case 0: src = Wo;      dst = t_oa; K = 256;  N = 192;  noff = 0;   break;
      case 1: src = Wa;      dst = t_oa; K = 256;  N = 96;   noff = 192; break;
      case 2: src = nullptr; dst = t_oa; K = 256;  N = 96;   noff = 288; break;
      case 3: src = Wv;      dst = t_v;  K = 256;  N = 256;  noff = 0;   break;
      case 4: src = Wp;      dst = t_p;  K = 256;  N = 256;  noff = 0;   break;
      case 5: src = Wf1;     dst = t_f1; K = 256;  N = 1024; noff = 0;   break;
      default: src = Wf2;    dst = t_f2; K = 1024; N = 256;  noff = 0;   break;
    }
    const int tilesK = K >> 5;
    const int nt = tilesK * (N >> 5);
    if (bxa >= nt) return;
    const int tk = bxa % tilesK, tn = bxa / tilesK;
    const int k0 = tk * 32, n0 = tn * 32;
    const int r = t >> 3, c4 = (t & 7) * 4;
    float4 v = make_float4(0.f, 0.f, 0.f, 0.f);
    if (src) v = *(const float4*)(src + (size_t)(k0 + r) * N + n0 + c4);
    tile[r][c4] = v.x; tile[r][c4 + 1] = v.y; tile[r][c4 + 2] = v.z; tile[r][c4 + 3] = v.w;
    __syncthreads();
    const int nn = t >> 3, kc = (t & 7) * 4;
    s16x4 o;
    o.x = f2b(tile[kc][nn]); o.y = f2b(tile[kc + 1][nn]);
    o.z = f2b(tile[kc + 2][nn]); o.w = f2b(tile[kc + 3][nn]);
    *(s16x4*)(dst + (size_t)(noff + n0 + nn) * K + k0 + kc) = o;
  } else if (blk < 1792 + 3169) {
    const int i = ((blk - 1792) * 256 + t) * 4;
    if (i >= 12672 * 256) return;
    s16x4 o = (s16x4){0, 0, 0, 0};
    if (i < 12600 * 256) {
      float4 v = *(const float4*)(value + i);
      o.x = f2b(v.x); o.y = f2b(v.y); o.z = f2b(v.z); o.w = f2b(v.w);
    }
    *(s16x4*)(valbf + i) = o;
  } else {
    const int row  = (blk - 4961) * 4 + (t >> 6);
    const int lane = t & 63;
    const float4 v = ((const float4*)(query + (size_t)row * 256))[lane];
    float s = v.x + v.y + v.z + v.w;
#pragma unroll
    for (int o = 32; o; o >>= 1) s += __shfl_xor(s, o);
    const float mean = s * (1.f / 256.f);
    const float dx = v.x - mean, dy = v.y - mean, dz = v.z - mean, dw = v.w - mean;
    float s2 = dx * dx + dy * dy + dz * dz + dw * dw;
#pragma unroll
    for (int o = 32; o; o >>= 1) s2 += __shfl_xor(s2, o);
    const float inv = rsqrtf(s2 * (1.f / 256.f) + 1e-5f);
    const float4 gv = ((const float4*)g1)[lane];
    const float4 bv = ((const float4*)b1)[lane];
    const float4 o1 = make_float4(dx * inv * gv.x + bv.x, dy * inv * gv.y + bv.y,
                                  dz * inv * gv.z + bv.z, dw * inv * gv.w + bv.w);
    s16x4 ob; ob.x = f2b(o1.x); ob.y = f2b(o1.y); ob.z = f2b(o1.z); ob.w = f2b(o1.w);
    ((s16x4*)(qnb + (size_t)row * 256))[lane] = ob;
    const float4 pv = ((const float4*)(query_pos + (size_t)row * 256))[lane];
    s16x4 op;
    op.x = f2b(o1.x + pv.x); op.y = f2b(o1.y + pv.y);
    op.z = f2b(o1.z + pv.z); op.w = f2b(o1.w + pv.w);
    ((s16x4*)(qa + (size_t)row * 256))[lane] = op;
  }
}

// ---------------------------------------------------------------------------
// deform_fused: block = 8 rows. Phase 1 (64 threads): softmax + bilinear
// setup -> LDS tables (oa now bf16). Phase 2 (256 threads): gather+FMA.
// ---------------------------------------------------------------------------
__global__ __launch_bounds__(256) void deform_fused(
    const short* __restrict__ vproj, const short* __restrict__ oa,
    const float* __restrict__ refp, short* __restrict__ out)
{
  __shared__ int4 sIdx[768];
  __shared__ s16x4 sW[768];
  const int t = threadIdx.x;

  if (t < 64) {
    const int row = blockIdx.x * 8 + (t >> 3), h = t & 7;
    const short* oarow = oa + (size_t)row * 288;
    float off[24];
    {
      const short8* op = (const short8*)(oarow + h * 24);  // 48 B, 16B-aligned
      b8f(op[0], off); b8f(op[1], off + 8); b8f(op[2], off + 16);
    }
    float lg[12];
    {
      const s16x4* ap = (const s16x4*)(oarow + 192 + h * 12);  // 8B-aligned
#pragma unroll
      for (int i = 0; i < 3; i++) {
        const s16x4 v = ap[i];
        lg[i * 4] = b2f(v.x); lg[i * 4 + 1] = b2f(v.y);
        lg[i * 4 + 2] = b2f(v.z); lg[i * 4 + 3] = b2f(v.w);
      }
    }
    const float* rp = refp + (size_t)row * 6;
    const float Rx[3] = {rp[0], rp[2], rp[4]}, Ry[3] = {rp[1], rp[3], rp[5]};
    float mx = lg[0];
#pragma unroll
    for (int i = 1; i < 12; i++) mx = fmaxf(mx, lg[i]);
    float sum = 0.f;
#pragma unroll
    for (int i = 0; i < 12; i++) { lg[i] = __expf(lg[i] - mx); sum += lg[i]; }
    const float inv = 1.f / sum;
    const int b = row >> 13;
    const int Hs[3] = {60, 30, 15}, Ws[3] = {80, 40, 20}, St[3] = {0, 4800, 6000};
#pragma unroll
    for (int p = 0; p < 12; p++) {
      const int l = p >> 2;
      const int W = Ws[l], H = Hs[l];
      const float gx = Rx[l] * W + off[p * 2]     - 0.5f;
      const float gy = Ry[l] * H + off[p * 2 + 1] - 0.5f;
      const float x0f = floorf(gx), y0f = floorf(gy);
      const float wx = gx - x0f, wy = gy - y0f;
      const int x0 = (int)x0f, y0 = (int)y0f;
      const float aw = lg[p] * inv;
      float cw[4] = {(1.f - wx) * (1.f - wy), wx * (1.f - wy),
                     (1.f - wx) * wy, wx * wy};
      const int base = b * 6300 + St[l];
      int ci[4];
#pragma unroll
      for (int k = 0; k < 4; k++) {
        const int xx = x0 + (k & 1), yy = y0 + (k >> 1);
        const bool valid = (xx >= 0) & (xx < W) & (yy >= 0) & (yy < H);
        const int xc = min(max(xx, 0), W - 1);
        const int yc = min(max(yy, 0), H - 1);
        ci[k] = ((base + yc * W + xc) << 8) + h * 32;
        cw[k] = valid ? cw[k] * aw : 0.f;
      }
      sIdx[t * 12 + p] = make_int4(ci[0], ci[1], ci[2], ci[3]);
      s16x4 wv; wv.x = f2b(cw[0]); wv.y = f2b(cw[1]); wv.z = f2b(cw[2]); wv.w = f2b(cw[3]);
      sW[t * 12 + p] = wv;
    }
  }
  __syncthreads();

  const int lu = t >> 2, c4 = (t & 3) * 8;
  float acc[8];
#pragma unroll
  for (int i = 0; i < 8; i++) acc[i] = 0.f;
#pragma unroll 2
  for (int p = 0; p < 12; p++) {
    const int4 idx = sIdx[lu * 12 + p];
    const s16x4 wb = sW[lu * 12 + p];
    const float w0 = b2f(wb.x), w1 = b2f(wb.y), w2 = b2f(wb.z), w3 = b2f(wb.w);
    const short8 v0 = *(const short8*)(vproj + idx.x + c4);
    const short8 v1 = *(const short8*)(vproj + idx.y + c4);
    const short8 v2 = *(const short8*)(vproj + idx.z + c4);
    const short8 v3 = *(const short8*)(vproj + idx.w + c4);
    float f0[8], f1[8], f2[8], f3[8];
    b8f(v0, f0); b8f(v1, f1); b8f(v2, f2); b8f(v3, f3);
#pragma unroll
    for (int j = 0; j < 8; j++)
      acc[j] += w0 * f0[j] + w1 * f1[j] + w2 * f2[j] + w3 * f3[j];
  }
  short8 o;
#pragma unroll
  for (int j = 0; j < 8; j++) o[j] = f2b(acc[j]);
  *(short8*)(out + (size_t)(blockIdx.x * 256 + t) * 8) = o;
}

// ---------------------------------------------------------------------------
// Launch
// ---------------------------------------------------------------------------
extern "C" void kernel_launch(void* const* d_in, const int* in_sizes, int n_in,
                              void* d_out, int out_size, void* d_ws, size_t ws_size,
                              hipStream_t stream)
{
  const float* query     = (const float*)d_in[0];
  const float* value     = (const float*)d_in[1];
  const float* query_pos = (const float*)d_in[2];
  const float* ref_pts   = (const float*)d_in[3];
  const float* g1  = (const float*)d_in[6];
  const float* b1  = (const float*)d_in[7];
  const float* Wo  = (const float*)d_in[8];
  const float* bo  = (const float*)d_in[9];
  const float* Wa  = (const float*)d_in[10];
  const float* ba  = (const float*)d_in[11];
  const float* Wv  = (const float*)d_in[12];
  const float* bv  = (const float*)d_in[13];
  const float* Wp  = (const float*)d_in[14];
  const float* bp  = (const float*)d_in[15];
  const float* g2  = (const float*)d_in[16];
  const float* b2  = (const float*)d_in[17];
  const float* Wf1 = (const float*)d_in[18];
  const float* bf1 = (const float*)d_in[19];
  const float* Wf2 = (const float*)d_in[20];
  const float* bf2 = (const float*)d_in[21];

  char* ws = (char*)d_ws;
  short* wt_oa   = (short*)(ws + 0);          // 384x256 bf16
  short* wt_v    = (short*)(ws + 196608);
  short* wt_p    = (short*)(ws + 327680);
  short* wt_f1   = (short*)(ws + 458752);
  short* wt_f2   = (short*)(ws + 983040);
  short* qnb     = (short*)(ws + 1507328);    // 16384x256 bf16 (LN1, no pos)
  short* qa      = (short*)(ws + 18284544);   // 16384x256 bf16 (later q2)
  short* oabuf   = (short*)(ws + 26673152);   // 16384x288 bf16 (9.4 MB)
  short* vproj   = (short*)(ws + 45547520);   // 12600x256 bf16
  short* sampled = (short*)(ws + 51998720);   // 16384x256 bf16
  float* qbuf    = (float*)(ws + 60387328);   // 16384x256 f32
  short* valbf   = (short*)(ws + 77164544);   // 12672x256 bf16
  short* q2      = qa;                        // reuse (qa dead after oa GEMM)
  short* hidden  = (short*)(ws + 26673152);   // 16384x1024 bf16
  float* outp = (float*)d_out;

  // 1. merged: weight convert + value convert + LN1
  prep_all<<<9057, 256, 0, stream>>>(Wo, Wa, Wv, Wp, Wf1, Wf2,
                                     wt_oa, wt_v, wt_p, wt_f1, wt_f2,
                                     value, valbf, query, query_pos,
                                     g1, b1, qnb, qa);
  // 2. merged GEMMs: oa (768 blocks, bf16 out) + vproj (394 blocks)
  gemm_oa_v<<<1162, 256, 0, stream>>>(qa, wt_oa, bo, ba, oabuf,
                                      valbf, wt_v, bv, vproj);
  // 3. fused prep+gather -> sampled bf16
  deform_fused<<<2048, 256, 0, stream>>>(vproj, oabuf, ref_pts, sampled);
  // 4. qbuf = sampled@Wp + bp + b2f(qnb) + query; q2 = LN(qbuf)  (fused)
  gemm_wp_ln2<<<512, 256, 0, stream>>>(sampled, wt_p, bp, qnb, query,
                                       g2, b2, qbuf, q2);
  // 5. hidden = gelu(q2 @ Wf1 + bf1) bf16  (64x128, 2048 blocks = 6/CU)
  gemm64_k<1><<<dim3(8, 256), 256, 0, stream>>>(q2, wt_f1, bf1, nullptr,
                                                hidden, 16384, 1024, 1024, 256);
  // 6. out = qbuf + hidden @ Wf2 + bf2  (64x128, 512 blocks, K=1024)
  gemm64_k<3><<<dim3(2, 256), 256, 0, stream>>>(hidden, wt_f2, bf2, qbuf,
                                                outp, 16384, 256, 256, 1024);
}